// Round 18
// baseline (339.518 us; speedup 1.0000x reference)
//
#include <hip/hip_runtime.h>
#include <hip/hip_bf16.h>
#include <stdint.h>

// GWNN: out = L2(relu(L1(x))),  L(x) = W_wav · diag(f) · W_inv · (x·W)
// R18: staged-bytes model (fit across R2-R17): GEMM time ~ total gload_lds
// bytes / 6.3 TB/s. Reduce staged bytes via B amortization: BM=256 (B staged
// per block amortized over 2x rows), BK=32, split-K x8, grid (32,8)=256
// blocks = 1/CU. Staged/GEMM: 384 MB (R14) -> 320 MB. Step count stays 32
// (tax unchanged). NBUF=3 ring (120KB LDS), PRE=2, vmcnt(10)/step -- the
// proven R14 pipeline shape. 8-way f32 partials + extended reduce kernels.

typedef __attribute__((ext_vector_type(4))) float f32x4;
typedef __attribute__((ext_vector_type(8))) short s16x8;
typedef __attribute__((ext_vector_type(4))) short s16x4;

#define DEVI static __device__ __forceinline__

DEVI short bf1(float x){ __bf16 h = (__bf16)x; return __builtin_bit_cast(short, h); }

DEVI s16x8 cvt8(f32x4 lo, f32x4 hi){
  s16x8 r;
#pragma unroll
  for (int i = 0; i < 4; ++i){ r[i] = bf1(lo[i]); r[4+i] = bf1(hi[i]); }
  return r;
}

DEVI void glds16(const void* g, void* l){
  __builtin_amdgcn_global_load_lds((const __attribute__((address_space(1))) void*)g,
                                   (__attribute__((address_space(3))) void*)l, 16, 0, 0);
}

template<int N> DEVI void waitvm(){
  if constexpr (N == 0)       asm volatile("s_waitcnt vmcnt(0)"  ::: "memory");
  else if constexpr (N == 5)  asm volatile("s_waitcnt vmcnt(5)"  ::: "memory");
  else if constexpr (N == 6)  asm volatile("s_waitcnt vmcnt(6)"  ::: "memory");
  else if constexpr (N == 10) asm volatile("s_waitcnt vmcnt(10)" ::: "memory");
}

// ============================================================================
// Big GEMM, BM=256, BK=32, split-K x8: P[kq][M][128] = A(f32) @ Bt^T.
// Wave w owns A rows [64w, 64w+64) (LDS reads dedup'd); acc[4][8],
// 32 MFMA/wave/step. Per stage per wave: 8 A + 2 B gload_lds = 10 vmcnt ops.
// A LDS row = 128 B (8 x 16B units, XOR ^(r&7)); B row = 64 B (4 units, ^(n&3)).
// T1 swizzle: bxl = (bx&7)*4 + (bx>>3)  (bijective over 32 tiles; each XCD
// owns a contiguous 1024-row A slab).
// ============================================================================
__global__ __launch_bounds__(256, 1) void gemm_big(
    const float* __restrict__ Ap, const short* __restrict__ Btp,
    float* __restrict__ Pp, int K, int M)
{
  constexpr int BM = 256, BK = 32;
  constexpr int ASZ = BM*BK*4;     // 32 KB fp32 A tile
  constexpr int BSZ = 128*BK*2;    // 8 KB B tile
  constexpr int TSZ = ASZ + BSZ;   // 40 KB
  constexpr int NBUF = 3, PRE = 2; // 120 KB LDS
  __shared__ uint8_t lds[NBUF*TSZ];

  const int tid  = threadIdx.x;
  const int lane = tid & 63;
  const int wv   = tid >> 6;
  const int la   = lane & 15;
  const int g4   = lane >> 4;
  const int bxl  = ((blockIdx.x & 7) << 2) + (blockIdx.x >> 3);  // T1, 32 tiles
  const int m0   = bxl * BM;
  const int kq   = blockIdx.y;
  const int K8   = K >> 3;
  const int kb   = kq * K8;

  // ---- A staging: wave w, instr j (0..7) stages rows 64w+8j..+7 (1KB each).
  const float* gAbase = Ap + (size_t)m0*K + kb;
  int aoffg[8];
#pragma unroll
  for (int j = 0; j < 8; ++j){
    const int rl = (wv<<6) + (j<<3) + (lane>>3);        // local row 0..255
    aoffg[j] = rl*K + (((lane&7) ^ (rl&7))<<2);         // float offset
  }

  // ---- B staging: wave w, instr i (0..1) stages rows 32w+16i..+15 (1KB each).
  const int nb0 = (wv<<5) + (lane>>2);
  const short* gB0 = Btp + (size_t)(nb0    )*K + kb + (((lane&3)^(nb0&3))<<3);
  const short* gB1 = Btp + (size_t)(nb0+16 )*K + kb + (((lane&3)^(nb0&3))<<3);

  // ---- fragment LDS byte offsets (XOR-swizzled reads), wave-private A rows
  int aoff[4][2];      // [mi][part]; A row = 8 x 16B units
#pragma unroll
  for (int mi = 0; mi < 4; ++mi){
    const int r = (wv<<6) + mi*16 + la;                 // rows 64w..64w+63
#pragma unroll
    for (int p = 0; p < 2; ++p)
      aoff[mi][p] = r*128 + ((((g4<<1)+p) ^ (r&7))<<4);
  }
  int boff[8];         // [ni]; B row = 4 x 16B units, unit g4
#pragma unroll
  for (int ni = 0; ni < 8; ++ni){
    const int n = ni*16 + la;
    boff[ni] = n*64 + ((g4 ^ (n&3))<<4);
  }

  f32x4 acc[4][8] = {};

  int kk = 0;                                // A/B k-advance (elements)
  uint8_t* const lend = lds + NBUF*TSZ;
  uint8_t* bs = lds;
  uint8_t* bc = lds;

  auto STAGE = [&](){
    uint8_t* Ab = bs;
    uint8_t* Bb = bs + ASZ;
#pragma unroll
    for (int j = 0; j < 8; ++j)
      glds16(gAbase + aoffg[j] + kk, Ab + (wv<<13) + (j<<10));
    glds16(gB0, Bb + (wv<<11));
    glds16(gB1, Bb + (wv<<11) + 1024);
    gB0 += BK; gB1 += BK;
    kk += BK;
    bs += TSZ; if (bs == lend) bs = lds;
  };

  auto COMPUTE = [&](){
    const uint8_t* Ab = bc;
    const uint8_t* Bb = bc + ASZ;
    s16x8 a0 = cvt8(*(const f32x4*)(Ab + aoff[0][0]), *(const f32x4*)(Ab + aoff[0][1]));
    s16x8 a1 = cvt8(*(const f32x4*)(Ab + aoff[1][0]), *(const f32x4*)(Ab + aoff[1][1]));
    s16x8 a2 = cvt8(*(const f32x4*)(Ab + aoff[2][0]), *(const f32x4*)(Ab + aoff[2][1]));
    s16x8 a3 = cvt8(*(const f32x4*)(Ab + aoff[3][0]), *(const f32x4*)(Ab + aoff[3][1]));
#pragma unroll
    for (int ni = 0; ni < 8; ++ni){
      s16x8 b = *(const s16x8*)(Bb + boff[ni]);
      acc[0][ni] = __builtin_amdgcn_mfma_f32_16x16x32_bf16(a0, b, acc[0][ni], 0, 0, 0);
      acc[1][ni] = __builtin_amdgcn_mfma_f32_16x16x32_bf16(a1, b, acc[1][ni], 0, 0, 0);
      acc[2][ni] = __builtin_amdgcn_mfma_f32_16x16x32_bf16(a2, b, acc[2][ni], 0, 0, 0);
      acc[3][ni] = __builtin_amdgcn_mfma_f32_16x16x32_bf16(a3, b, acc[3][ni], 0, 0, 0);
    }
    bc += TSZ; if (bc == lend) bc = lds;
  };

  const int ns = K8 >> 5;                    // 32 steps (K8=1024, BK=32)
  for (int s = 0; s < PRE && s < ns; ++s) STAGE();

  for (int t = 0; t < ns; ++t){
    if (t < ns - 1) waitvm<10>();            // stage t landed; t+1 in flight
    else            waitvm<0>();
    __builtin_amdgcn_s_barrier();
    asm volatile("" ::: "memory");
    if (t + PRE < ns) STAGE();
    COMPUTE();
    asm volatile("" ::: "memory");
  }

  // ---- partial epilogue: f32 P[kq][M][128]
  float* P = Pp + (size_t)kq * M * 128;
  const int rbase = m0 + (wv<<6) + (g4<<2);
#pragma unroll
  for (int mi = 0; mi < 4; ++mi)
#pragma unroll
    for (int ni = 0; ni < 8; ++ni)
#pragma unroll
      for (int r = 0; r < 4; ++r)
        P[(size_t)(rbase + mi*16 + r)*128 + ni*16 + la] = acc[mi][ni][r];
}

// ============================================================================
// Small K=128 GEMM (proven): out = bf16 transposed [128][M].
// ============================================================================
template<bool ABF>
__global__ __launch_bounds__(256, 1) void sgemm(
    const void* __restrict__ Ap, const short* __restrict__ Btp,
    void* __restrict__ Outp, int K, int M)
{
  constexpr int BM = 32, BN = 128, BK = 64;
  constexpr int ASZ = ABF ? BM*BK*2 : BM*BK*4;
  constexpr int BSZ = BN*BK*2;
  constexpr int TSZ = ASZ + BSZ;
  constexpr int NL  = ABF ? 5 : 6;
  constexpr int NBUF = 3, PRE = 2;
  __shared__ uint8_t lds[NBUF*TSZ];

  const int tid  = threadIdx.x;
  const int lane = tid & 63;
  const int wv   = tid >> 6;
  const int la   = lane & 15;
  const int g4   = lane >> 4;
  const int m0   = blockIdx.x * BM;

  const float* gA0 = nullptr; const float* gA1 = nullptr; const short* gAh = nullptr;
  if constexpr (!ABF){
    const float* Af = (const float*)Ap;
    int r0 = (wv<<3) + (lane>>4);
    int r1 = r0 + 4;
    gA0 = Af + (size_t)(m0+r0)*K + (((lane&15)^(r0&15))<<2);
    gA1 = Af + (size_t)(m0+r1)*K + (((lane&15)^(r1&15))<<2);
  } else {
    const short* Ah = (const short*)Ap;
    int r = (wv<<3) + (lane>>3);
    gAh = Ah + (size_t)(m0+r)*K + (((lane&7)^(r&7))<<3);
  }
  const int nb0 = (wv<<5) + (lane>>3);
  const short* gB0 = Btp + (size_t)(nb0    )*K + (((lane&7)^(nb0&7))<<3);
  const short* gB1 = Btp + (size_t)(nb0+ 8 )*K + (((lane&7)^(nb0&7))<<3);
  const short* gB2 = Btp + (size_t)(nb0+16 )*K + (((lane&7)^(nb0&7))<<3);
  const short* gB3 = Btp + (size_t)(nb0+24 )*K + (((lane&7)^(nb0&7))<<3);

  int aoff[2][2][2];
  int boff[2][2];
#pragma unroll
  for (int mi = 0; mi < 2; ++mi){
    const int r = mi*16 + la;
#pragma unroll
    for (int kf = 0; kf < 2; ++kf){
      if constexpr (!ABF){
        const int v0 = kf*8 + (g4<<1);
        aoff[mi][kf][0] = r*256 + (((v0  )^(r&15))<<4);
        aoff[mi][kf][1] = r*256 + (((v0+1)^(r&15))<<4);
      } else {
        const int u = kf*4 + g4;
        aoff[mi][kf][0] = r*128 + ((u^(r&7))<<4);
        aoff[mi][kf][1] = 0;
      }
    }
  }
#pragma unroll
  for (int ni = 0; ni < 2; ++ni){
    const int n = (wv<<5) + ni*16 + la;
#pragma unroll
    for (int kf = 0; kf < 2; ++kf){
      const int u = kf*4 + g4;
      boff[ni][kf] = n*128 + ((u^(n&7))<<4);
    }
  }

  f32x4 acc[2][2] = {};

  auto STAGE = [&](uint8_t* buf){
    uint8_t* Ab = buf;
    uint8_t* Bb = buf + ASZ;
    if constexpr (!ABF){
      glds16(gA0, Ab + (wv<<11));
      glds16(gA1, Ab + (wv<<11) + 1024);
      gA0 += BK; gA1 += BK;
    } else {
      glds16(gAh, Ab + (wv<<10));
      gAh += BK;
    }
    glds16(gB0, Bb + (wv<<12));
    glds16(gB1, Bb + (wv<<12) + 1024);
    glds16(gB2, Bb + (wv<<12) + 2048);
    glds16(gB3, Bb + (wv<<12) + 3072);
    gB0 += BK; gB1 += BK; gB2 += BK; gB3 += BK;
  };

  auto COMPUTE = [&](const uint8_t* buf){
    const uint8_t* Ab = buf;
    const uint8_t* Bb = buf + ASZ;
#pragma unroll
    for (int kf = 0; kf < 2; ++kf){
      s16x8 a0, a1, b0, b1;
      if constexpr (!ABF){
        a0 = cvt8(*(const f32x4*)(Ab + aoff[0][kf][0]), *(const f32x4*)(Ab + aoff[0][kf][1]));
        a1 = cvt8(*(const f32x4*)(Ab + aoff[1][kf][0]), *(const f32x4*)(Ab + aoff[1][kf][1]));
      } else {
        a0 = *(const s16x8*)(Ab + aoff[0][kf][0]);
        a1 = *(const s16x8*)(Ab + aoff[1][kf][0]);
      }
      b0 = *(const s16x8*)(Bb + boff[0][kf]);
      b1 = *(const s16x8*)(Bb + boff[1][kf]);
      acc[0][0] = __builtin_amdgcn_mfma_f32_16x16x32_bf16(a0, b0, acc[0][0], 0, 0, 0);
      acc[0][1] = __builtin_amdgcn_mfma_f32_16x16x32_bf16(a0, b1, acc[0][1], 0, 0, 0);
      acc[1][0] = __builtin_amdgcn_mfma_f32_16x16x32_bf16(a1, b0, acc[1][0], 0, 0, 0);
      acc[1][1] = __builtin_amdgcn_mfma_f32_16x16x32_bf16(a1, b1, acc[1][1], 0, 0, 0);
    }
  };

  const int ns = K >> 6;
  uint8_t* const lend = lds + NBUF*TSZ;
  uint8_t* bs = lds;
  uint8_t* bc = lds;
  for (int s = 0; s < PRE && s < ns; ++s){
    STAGE(bs);
    bs += TSZ; if (bs == lend) bs = lds;
  }
  for (int t = 0; t < ns; ++t){
    if (t < ns - 1) waitvm<NL>(); else waitvm<0>();
    __builtin_amdgcn_s_barrier();
    asm volatile("" ::: "memory");
    if (t + PRE < ns){
      STAGE(bs);
      bs += TSZ; if (bs == lend) bs = lds;
    }
    COMPUTE(bc);
    bc += TSZ; if (bc == lend) bc = lds;
    asm volatile("" ::: "memory");
  }

  const int mbase = m0 + (g4<<2);
  const int nc0   = (wv<<5) + la;
#pragma unroll
  for (int mi = 0; mi < 2; ++mi){
#pragma unroll
    for (int ni = 0; ni < 2; ++ni){
      s16x4 pk;
#pragma unroll
      for (int r = 0; r < 4; ++r) pk[r] = bf1(acc[mi][ni][r]);
      *(s16x4*)((short*)Outp + (size_t)(nc0 + (ni<<4))*M + (mbase + (mi<<4))) = pk;
    }
  }
}

// ============================================================================
// Reduce kernels: combine 8 K-eighth partials P[8][M][128] (f32, fixed order).
// ============================================================================

DEVI f32x4 sum8(const float* p, size_t S){
  f32x4 v = (*(const f32x4*)(p)       + *(const f32x4*)(p +   S))
          + (*(const f32x4*)(p + 2*S) + *(const f32x4*)(p + 3*S));
  f32x4 w = (*(const f32x4*)(p + 4*S) + *(const f32x4*)(p + 5*S))
          + (*(const f32x4*)(p + 6*S) + *(const f32x4*)(p + 7*S));
  return v + w;
}

__global__ __launch_bounds__(256) void red_t(
    const float* __restrict__ Pp, const float* __restrict__ fp,
    short* __restrict__ out, int M)
{
  __shared__ short t[128*65];
  const size_t S = (size_t)M*128;
  const int m0 = blockIdx.x * 64;
  const int tid = threadIdx.x;
#pragma unroll
  for (int it = 0; it < 8; ++it){
    const int idx = it*256 + tid;
    const int m = idx >> 5, nq = idx & 31;
    f32x4 v = sum8(Pp + (size_t)(m0+m)*128 + nq*4, S);
    const float fv = fp[m0+m];
#pragma unroll
    for (int j = 0; j < 4; ++j)
      t[(nq*4+j)*65 + m] = bf1(fv * v[j]);
  }
  __syncthreads();
#pragma unroll
  for (int it = 0; it < 8; ++it){
    const int idx = it*256 + tid;
    const int n = idx >> 4, mc = idx & 15;
    s16x4 v;
#pragma unroll
    for (int j = 0; j < 4; ++j) v[j] = t[n*65 + mc*4 + j];
    *(s16x4*)(out + (size_t)n*M + m0 + mc*4) = v;
  }
}

__global__ __launch_bounds__(256) void red_r(
    const float* __restrict__ Pp, short* __restrict__ out, int M)
{
  const size_t S = (size_t)M*128;
  const size_t i0 = (size_t)(blockIdx.x*256 + threadIdx.x) * 8;
  s16x8 v;
#pragma unroll
  for (int h = 0; h < 2; ++h){
    f32x4 a = sum8(Pp + i0 + 4*h, S);
#pragma unroll
    for (int j = 0; j < 4; ++j)
      v[4*h+j] = bf1(fmaxf(a[j], 0.0f));
  }
  *(s16x8*)(out + i0) = v;
}

__global__ __launch_bounds__(256) void red_f(
    const float* __restrict__ Pp, float* __restrict__ out, int M)
{
  const size_t S = (size_t)M*128;
  const size_t i0 = (size_t)(blockIdx.x*256 + threadIdx.x) * 4;
  *(f32x4*)(out + i0) = sum8(Pp + i0, S);
}

// W1T[n][k] = bf16(W1[k][n]), same for W2 — tiny one-shot transpose.
__global__ void wtrans_k(const float* __restrict__ W1, const float* __restrict__ W2,
                         short* __restrict__ T1, short* __restrict__ T2){
  const int idx = blockIdx.x*256 + threadIdx.x;
  const int m = idx >> 14, rem = idx & 16383;
  const int n = rem >> 7, k = rem & 127;
  const float* W = m ? W2 : W1;
  short* T = m ? T2 : T1;
  T[n*128 + k] = bf1(W[k*128 + n]);
}

extern "C" void kernel_launch(void* const* d_in, const int* in_sizes, int n_in,
                              void* d_out, int out_size, void* d_ws, size_t ws_size,
                              hipStream_t stream){
  const float* input = (const float*)d_in[0];
  const float* wav   = (const float*)d_in[1];
  const float* winv  = (const float*)d_in[2];
  const float* W1    = (const float*)d_in[3];
  const float* f1    = (const float*)d_in[4];
  const float* W2    = (const float*)d_in[5];
  const float* f2    = (const float*)d_in[6];

  constexpr int M = 8192;
  uint8_t* ws = (uint8_t*)d_ws;
  short* W1T = (short*)(ws);                        // 32 KB  [n][k]
  short* W2T = (short*)(ws + (32<<10));             // 32 KB  [n][k]
  short* XWT = (short*)(ws + (64<<10));             // 2 MB   [128][M] bf16
  short* SPT = (short*)(ws + (64<<10) + (2<<20));   // 2 MB   [128][M] bf16
  short* H1  = (short*)(ws + (64<<10) + (4<<20));   // 2 MB   [M][128] bf16
  float* P   = (float*)(ws + (64<<10) + (6<<20));   // 32 MB  f32 [8][M][128]

  dim3 b(256);
  dim3 gbig(M/256, 8);       // 32 x 8 = 256 blocks, 1/CU
  dim3 gns(M/32);            // small K=128 GEMM
  dim3 grt(M/64);            // red_t
  dim3 grr(M*128/(256*8));   // red_r
  dim3 grf(M*128/(256*4));   // red_f
  dim3 gt(128);

  wtrans_k<<<gt, b, 0, stream>>>(W1, W2, W1T, W2T);
  // layer 1
  sgemm<false><<<gns, b, 0, stream>>>(input, W1T, XWT, 128, M);
  gemm_big<<<gbig, b, 0, stream>>>(winv, XWT, P, M, M);
  red_t  <<<grt, b, 0, stream>>>(P, f1, SPT, M);
  gemm_big<<<gbig, b, 0, stream>>>(wav, SPT, P, M, M);
  red_r  <<<grr, b, 0, stream>>>(P, H1, M);
  // layer 2
  sgemm<true ><<<gns, b, 0, stream>>>(H1, W2T, XWT, 128, M);
  gemm_big<<<gbig, b, 0, stream>>>(winv, XWT, P, M, M);
  red_t  <<<grt, b, 0, stream>>>(P, f2, SPT, M);
  gemm_big<<<gbig, b, 0, stream>>>(wav, SPT, P, M, M);
  red_f  <<<grf, b, 0, stream>>>(P, (float*)d_out, M);
}

// Round 19
// 325.690 us; speedup vs baseline: 1.0425x; 1.0425x over previous
//
#include <hip/hip_runtime.h>
#include <hip/hip_bf16.h>
#include <stdint.h>

// GWNN: out = L2(relu(L1(x))),  L(x) = W_wav · diag(f) · W_inv · (x·W)
// R19: staged-bytes model (R14 fit: 384MB/62us = 6.2 TB/s = 98% of achievable
// staging ceiling). Cut staged bytes KEEPING 256B requests (R18's BK=32 broke
// that): BM=256, BK=64, split-K x8, grid (32,8)=256 blocks (1/CU), NBUF=2 at
// exactly 160KB LDS, R17-proven 2-barrier schedule. Staged/GEMM: 384->320MB,
// steps 32->16 (tax halves). B staging path byte-identical to R14's proven one.

typedef __attribute__((ext_vector_type(4))) float f32x4;
typedef __attribute__((ext_vector_type(8))) short s16x8;
typedef __attribute__((ext_vector_type(4))) short s16x4;

#define DEVI static __device__ __forceinline__

DEVI short bf1(float x){ __bf16 h = (__bf16)x; return __builtin_bit_cast(short, h); }

DEVI s16x8 cvt8(f32x4 lo, f32x4 hi){
  s16x8 r;
#pragma unroll
  for (int i = 0; i < 4; ++i){ r[i] = bf1(lo[i]); r[4+i] = bf1(hi[i]); }
  return r;
}

DEVI void glds16(const void* g, void* l){
  __builtin_amdgcn_global_load_lds((const __attribute__((address_space(1))) void*)g,
                                   (__attribute__((address_space(3))) void*)l, 16, 0, 0);
}

template<int N> DEVI void waitvm(){
  if constexpr (N == 0)       asm volatile("s_waitcnt vmcnt(0)"  ::: "memory");
  else if constexpr (N == 5)  asm volatile("s_waitcnt vmcnt(5)"  ::: "memory");
  else if constexpr (N == 6)  asm volatile("s_waitcnt vmcnt(6)"  ::: "memory");
  else if constexpr (N == 20) asm volatile("s_waitcnt vmcnt(20)" ::: "memory");
}

// ============================================================================
// Big GEMM, BM=256, BK=64, split-K x8: P[kq][M][128] = A(f32) @ Bt^T.
// Wave w owns A rows [64w, 64w+64): acc[4][8], 64 MFMA/wave/step, 16 steps.
// Per stage per wave: 16 A + 4 B gload_lds = 20 vmcnt ops (all 1KB, >=256B
// per-row segments). NBUF=2 (160KB LDS), 2 barriers/step (R17 schedule).
// T1 swizzle: bxl = (bx&7)*4 + (bx>>3) (bijective over 32 tiles; each XCD
// owns a contiguous 1024-row A slab).
// ============================================================================
__global__ __launch_bounds__(256, 1) void gemm_big(
    const float* __restrict__ Ap, const short* __restrict__ Btp,
    float* __restrict__ Pp, int K, int M)
{
  constexpr int BM = 256, BK = 64;
  constexpr int ASZ = BM*BK*4;     // 64 KB fp32 A tile
  constexpr int BSZ = 128*BK*2;    // 16 KB B tile
  constexpr int TSZ = ASZ + BSZ;   // 80 KB
  constexpr int NBUF = 2;          // 160 KB LDS (full CU)
  __shared__ uint8_t lds[NBUF*TSZ];

  const int tid  = threadIdx.x;
  const int lane = tid & 63;
  const int wv   = tid >> 6;
  const int la   = lane & 15;
  const int g4   = lane >> 4;
  const int bxl  = ((blockIdx.x & 7) << 2) + (blockIdx.x >> 3);  // T1, 32 tiles
  const int m0   = bxl * BM;
  const int kq   = blockIdx.y;
  const int K8   = K >> 3;
  const int kb   = kq * K8;

  // ---- A staging: wave w, instr j (0..15) stages rows 64w+4j..+3 (1KB each).
  const float* gAbase = Ap + (size_t)m0*K + kb;
  int aoffg[16];
#pragma unroll
  for (int j = 0; j < 16; ++j){
    const int rl = (wv<<6) + (j<<2) + (lane>>4);        // local row 0..255
    aoffg[j] = rl*K + (((lane&15) ^ (rl&15))<<2);       // float offset
  }

  // ---- B staging (R14-proven): wave w stages rows 32w..32w+31, pre-swizzled
  const int nb0 = (wv<<5) + (lane>>3);
  const short* gB0 = Btp + (size_t)(nb0    )*K + kb + (((lane&7)^(nb0&7))<<3);
  const short* gB1 = Btp + (size_t)(nb0+ 8 )*K + kb + (((lane&7)^(nb0&7))<<3);
  const short* gB2 = Btp + (size_t)(nb0+16 )*K + kb + (((lane&7)^(nb0&7))<<3);
  const short* gB3 = Btp + (size_t)(nb0+24 )*K + kb + (((lane&7)^(nb0&7))<<3);

  // ---- fragment LDS byte offsets (XOR-swizzled reads), wave-private A rows
  int aoff[4][2][2];   // [mi][kf][part]; fp32 row = 16 x 16B units
#pragma unroll
  for (int mi = 0; mi < 4; ++mi){
    const int r = (wv<<6) + mi*16 + la;                 // rows 64w..64w+63
#pragma unroll
    for (int kf = 0; kf < 2; ++kf){
      const int v0 = kf*8 + (g4<<1);
      aoff[mi][kf][0] = r*256 + (((v0  )^(r&15))<<4);
      aoff[mi][kf][1] = r*256 + (((v0+1)^(r&15))<<4);
    }
  }
  int boff[8][2];      // [ni][kf]; all 128 cols per wave
#pragma unroll
  for (int ni = 0; ni < 8; ++ni){
    const int n = ni*16 + la;
#pragma unroll
    for (int kf = 0; kf < 2; ++kf){
      const int u = kf*4 + g4;
      boff[ni][kf] = n*128 + ((u^(n&7))<<4);
    }
  }

  f32x4 acc[4][8] = {};

  int kk = 0;                                // k-advance (elements)
  uint8_t* bs = lds;                         // NBUF=2: toggle
  uint8_t* bc = lds;

  auto STAGE = [&](){
    uint8_t* Ab = bs;
    uint8_t* Bb = bs + ASZ;
#pragma unroll
    for (int j = 0; j < 16; ++j)
      glds16(gAbase + aoffg[j] + kk, Ab + (wv<<14) + (j<<10));
    kk += BK;
    glds16(gB0, Bb + (wv<<12));
    glds16(gB1, Bb + (wv<<12) + 1024);
    glds16(gB2, Bb + (wv<<12) + 2048);
    glds16(gB3, Bb + (wv<<12) + 3072);
    gB0 += BK; gB1 += BK; gB2 += BK; gB3 += BK;
    bs = (bs == lds) ? lds + TSZ : lds;
  };

  auto COMPUTE = [&](){
    const uint8_t* Ab = bc;
    const uint8_t* Bb = bc + ASZ;
#pragma unroll
    for (int kf = 0; kf < 2; ++kf){
      s16x8 a0 = cvt8(*(const f32x4*)(Ab + aoff[0][kf][0]), *(const f32x4*)(Ab + aoff[0][kf][1]));
      s16x8 a1 = cvt8(*(const f32x4*)(Ab + aoff[1][kf][0]), *(const f32x4*)(Ab + aoff[1][kf][1]));
      s16x8 a2 = cvt8(*(const f32x4*)(Ab + aoff[2][kf][0]), *(const f32x4*)(Ab + aoff[2][kf][1]));
      s16x8 a3 = cvt8(*(const f32x4*)(Ab + aoff[3][kf][0]), *(const f32x4*)(Ab + aoff[3][kf][1]));
#pragma unroll
      for (int ni = 0; ni < 8; ++ni){
        s16x8 b = *(const s16x8*)(Bb + boff[ni][kf]);
        acc[0][ni] = __builtin_amdgcn_mfma_f32_16x16x32_bf16(a0, b, acc[0][ni], 0, 0, 0);
        acc[1][ni] = __builtin_amdgcn_mfma_f32_16x16x32_bf16(a1, b, acc[1][ni], 0, 0, 0);
        acc[2][ni] = __builtin_amdgcn_mfma_f32_16x16x32_bf16(a2, b, acc[2][ni], 0, 0, 0);
        acc[3][ni] = __builtin_amdgcn_mfma_f32_16x16x32_bf16(a3, b, acc[3][ni], 0, 0, 0);
      }
    }
    bc = (bc == lds) ? lds + TSZ : lds;
  };

  const int ns = K8 >> 6;                    // 16 steps
  STAGE();                                   // stage 0

  for (int t = 0; t < ns; ++t){
    if (t + 1 < ns){ STAGE(); waitvm<20>(); }   // stage t done; t+1 in flight
    else           { waitvm<0>(); }
    __builtin_amdgcn_s_barrier();            // buf(t) visible to all waves
    asm volatile("" ::: "memory");
    COMPUTE();
    asm volatile("" ::: "memory");
    __builtin_amdgcn_s_barrier();            // buf(t) free for restage
  }

  // ---- partial epilogue: f32 P[kq][M][128]
  float* P = Pp + (size_t)kq * M * 128;
  const int rbase = m0 + (wv<<6) + (g4<<2);
#pragma unroll
  for (int mi = 0; mi < 4; ++mi)
#pragma unroll
    for (int ni = 0; ni < 8; ++ni)
#pragma unroll
      for (int r = 0; r < 4; ++r)
        P[(size_t)(rbase + mi*16 + r)*128 + ni*16 + la] = acc[mi][ni][r];
}

// ============================================================================
// Small K=128 GEMM (proven): out = bf16 transposed [128][M].
// ============================================================================
template<bool ABF>
__global__ __launch_bounds__(256, 1) void sgemm(
    const void* __restrict__ Ap, const short* __restrict__ Btp,
    void* __restrict__ Outp, int K, int M)
{
  constexpr int BM = 32, BN = 128, BK = 64;
  constexpr int ASZ = ABF ? BM*BK*2 : BM*BK*4;
  constexpr int BSZ = BN*BK*2;
  constexpr int TSZ = ASZ + BSZ;
  constexpr int NL  = ABF ? 5 : 6;
  constexpr int NBUF = 3, PRE = 2;
  __shared__ uint8_t lds[NBUF*TSZ];

  const int tid  = threadIdx.x;
  const int lane = tid & 63;
  const int wv   = tid >> 6;
  const int la   = lane & 15;
  const int g4   = lane >> 4;
  const int m0   = blockIdx.x * BM;

  const float* gA0 = nullptr; const float* gA1 = nullptr; const short* gAh = nullptr;
  if constexpr (!ABF){
    const float* Af = (const float*)Ap;
    int r0 = (wv<<3) + (lane>>4);
    int r1 = r0 + 4;
    gA0 = Af + (size_t)(m0+r0)*K + (((lane&15)^(r0&15))<<2);
    gA1 = Af + (size_t)(m0+r1)*K + (((lane&15)^(r1&15))<<2);
  } else {
    const short* Ah = (const short*)Ap;
    int r = (wv<<3) + (lane>>3);
    gAh = Ah + (size_t)(m0+r)*K + (((lane&7)^(r&7))<<3);
  }
  const int nb0 = (wv<<5) + (lane>>3);
  const short* gB0 = Btp + (size_t)(nb0    )*K + (((lane&7)^(nb0&7))<<3);
  const short* gB1 = Btp + (size_t)(nb0+ 8 )*K + (((lane&7)^(nb0&7))<<3);
  const short* gB2 = Btp + (size_t)(nb0+16 )*K + (((lane&7)^(nb0&7))<<3);
  const short* gB3 = Btp + (size_t)(nb0+24 )*K + (((lane&7)^(nb0&7))<<3);

  int aoff[2][2][2];
  int boff[2][2];
#pragma unroll
  for (int mi = 0; mi < 2; ++mi){
    const int r = mi*16 + la;
#pragma unroll
    for (int kf = 0; kf < 2; ++kf){
      if constexpr (!ABF){
        const int v0 = kf*8 + (g4<<1);
        aoff[mi][kf][0] = r*256 + (((v0  )^(r&15))<<4);
        aoff[mi][kf][1] = r*256 + (((v0+1)^(r&15))<<4);
      } else {
        const int u = kf*4 + g4;
        aoff[mi][kf][0] = r*128 + ((u^(r&7))<<4);
        aoff[mi][kf][1] = 0;
      }
    }
  }
#pragma unroll
  for (int ni = 0; ni < 2; ++ni){
    const int n = (wv<<5) + ni*16 + la;
#pragma unroll
    for (int kf = 0; kf < 2; ++kf){
      const int u = kf*4 + g4;
      boff[ni][kf] = n*128 + ((u^(n&7))<<4);
    }
  }

  f32x4 acc[2][2] = {};

  auto STAGE = [&](uint8_t* buf){
    uint8_t* Ab = buf;
    uint8_t* Bb = buf + ASZ;
    if constexpr (!ABF){
      glds16(gA0, Ab + (wv<<11));
      glds16(gA1, Ab + (wv<<11) + 1024);
      gA0 += BK; gA1 += BK;
    } else {
      glds16(gAh, Ab + (wv<<10));
      gAh += BK;
    }
    glds16(gB0, Bb + (wv<<12));
    glds16(gB1, Bb + (wv<<12) + 1024);
    glds16(gB2, Bb + (wv<<12) + 2048);
    glds16(gB3, Bb + (wv<<12) + 3072);
    gB0 += BK; gB1 += BK; gB2 += BK; gB3 += BK;
  };

  auto COMPUTE = [&](const uint8_t* buf){
    const uint8_t* Ab = buf;
    const uint8_t* Bb = buf + ASZ;
#pragma unroll
    for (int kf = 0; kf < 2; ++kf){
      s16x8 a0, a1, b0, b1;
      if constexpr (!ABF){
        a0 = cvt8(*(const f32x4*)(Ab + aoff[0][kf][0]), *(const f32x4*)(Ab + aoff[0][kf][1]));
        a1 = cvt8(*(const f32x4*)(Ab + aoff[1][kf][0]), *(const f32x4*)(Ab + aoff[1][kf][1]));
      } else {
        a0 = *(const s16x8*)(Ab + aoff[0][kf][0]);
        a1 = *(const s16x8*)(Ab + aoff[1][kf][0]);
      }
      b0 = *(const s16x8*)(Bb + boff[0][kf]);
      b1 = *(const s16x8*)(Bb + boff[1][kf]);
      acc[0][0] = __builtin_amdgcn_mfma_f32_16x16x32_bf16(a0, b0, acc[0][0], 0, 0, 0);
      acc[0][1] = __builtin_amdgcn_mfma_f32_16x16x32_bf16(a0, b1, acc[0][1], 0, 0, 0);
      acc[1][0] = __builtin_amdgcn_mfma_f32_16x16x32_bf16(a1, b0, acc[1][0], 0, 0, 0);
      acc[1][1] = __builtin_amdgcn_mfma_f32_16x16x32_bf16(a1, b1, acc[1][1], 0, 0, 0);
    }
  };

  const int ns = K >> 6;
  uint8_t* const lend = lds + NBUF*TSZ;
  uint8_t* bs = lds;
  uint8_t* bc = lds;
  for (int s = 0; s < PRE && s < ns; ++s){
    STAGE(bs);
    bs += TSZ; if (bs == lend) bs = lds;
  }
  for (int t = 0; t < ns; ++t){
    if (t < ns - 1) waitvm<NL>(); else waitvm<0>();
    __builtin_amdgcn_s_barrier();
    asm volatile("" ::: "memory");
    if (t + PRE < ns){
      STAGE(bs);
      bs += TSZ; if (bs == lend) bs = lds;
    }
    COMPUTE(bc);
    bc += TSZ; if (bc == lend) bc = lds;
    asm volatile("" ::: "memory");
  }

  const int mbase = m0 + (g4<<2);
  const int nc0   = (wv<<5) + la;
#pragma unroll
  for (int mi = 0; mi < 2; ++mi){
#pragma unroll
    for (int ni = 0; ni < 2; ++ni){
      s16x4 pk;
#pragma unroll
      for (int r = 0; r < 4; ++r) pk[r] = bf1(acc[mi][ni][r]);
      *(s16x4*)((short*)Outp + (size_t)(nc0 + (ni<<4))*M + (mbase + (mi<<4))) = pk;
    }
  }
}

// ============================================================================
// Reduce kernels: combine 8 K-eighth partials P[8][M][128] (f32, fixed order).
// ============================================================================

DEVI f32x4 sum8(const float* p, size_t S){
  f32x4 v = (*(const f32x4*)(p)       + *(const f32x4*)(p +   S))
          + (*(const f32x4*)(p + 2*S) + *(const f32x4*)(p + 3*S));
  f32x4 w = (*(const f32x4*)(p + 4*S) + *(const f32x4*)(p + 5*S))
          + (*(const f32x4*)(p + 6*S) + *(const f32x4*)(p + 7*S));
  return v + w;
}

__global__ __launch_bounds__(256) void red_t(
    const float* __restrict__ Pp, const float* __restrict__ fp,
    short* __restrict__ out, int M)
{
  __shared__ short t[128*65];
  const size_t S = (size_t)M*128;
  const int m0 = blockIdx.x * 64;
  const int tid = threadIdx.x;
#pragma unroll
  for (int it = 0; it < 8; ++it){
    const int idx = it*256 + tid;
    const int m = idx >> 5, nq = idx & 31;
    f32x4 v = sum8(Pp + (size_t)(m0+m)*128 + nq*4, S);
    const float fv = fp[m0+m];
#pragma unroll
    for (int j = 0; j < 4; ++j)
      t[(nq*4+j)*65 + m] = bf1(fv * v[j]);
  }
  __syncthreads();
#pragma unroll
  for (int it = 0; it < 8; ++it){
    const int idx = it*256 + tid;
    const int n = idx >> 4, mc = idx & 15;
    s16x4 v;
#pragma unroll
    for (int j = 0; j < 4; ++j) v[j] = t[n*65 + mc*4 + j];
    *(s16x4*)(out + (size_t)n*M + m0 + mc*4) = v;
  }
}

__global__ __launch_bounds__(256) void red_r(
    const float* __restrict__ Pp, short* __restrict__ out, int M)
{
  const size_t S = (size_t)M*128;
  const size_t i0 = (size_t)(blockIdx.x*256 + threadIdx.x) * 8;
  s16x8 v;
#pragma unroll
  for (int h = 0; h < 2; ++h){
    f32x4 a = sum8(Pp + i0 + 4*h, S);
#pragma unroll
    for (int j = 0; j < 4; ++j)
      v[4*h+j] = bf1(fmaxf(a[j], 0.0f));
  }
  *(s16x8*)(out + i0) = v;
}

__global__ __launch_bounds__(256) void red_f(
    const float* __restrict__ Pp, float* __restrict__ out, int M)
{
  const size_t S = (size_t)M*128;
  const size_t i0 = (size_t)(blockIdx.x*256 + threadIdx.x) * 4;
  *(f32x4*)(out + i0) = sum8(Pp + i0, S);
}

// W1T[n][k] = bf16(W1[k][n]), same for W2 — tiny one-shot transpose.
__global__ void wtrans_k(const float* __restrict__ W1, const float* __restrict__ W2,
                         short* __restrict__ T1, short* __restrict__ T2){
  const int idx = blockIdx.x*256 + threadIdx.x;
  const int m = idx >> 14, rem = idx & 16383;
  const int n = rem >> 7, k = rem & 127;
  const float* W = m ? W2 : W1;
  short* T = m ? T2 : T1;
  T[n*128 + k] = bf1(W[k*128 + n]);
}

extern "C" void kernel_launch(void* const* d_in, const int* in_sizes, int n_in,
                              void* d_out, int out_size, void* d_ws, size_t ws_size,
                              hipStream_t stream){
  const float* input = (const float*)d_in[0];
  const float* wav   = (const float*)d_in[1];
  const float* winv  = (const float*)d_in[2];
  const float* W1    = (const float*)d_in[3];
  const float* f1    = (const float*)d_in[4];
  const float* W2    = (const float*)d_in[5];
  const float* f2    = (const float*)d_in[6];

  constexpr int M = 8192;
  uint8_t* ws = (uint8_t*)d_ws;
  short* W1T = (short*)(ws);                        // 32 KB  [n][k]
  short* W2T = (short*)(ws + (32<<10));             // 32 KB  [n][k]
  short* XWT = (short*)(ws + (64<<10));             // 2 MB   [128][M] bf16
  short* SPT = (short*)(ws + (64<<10) + (2<<20));   // 2 MB   [128][M] bf16
  short* H1  = (short*)(ws + (64<<10) + (4<<20));   // 2 MB   [M][128] bf16
  float* P   = (float*)(ws + (64<<10) + (6<<20));   // 32 MB  f32 [8][M][128]

  dim3 b(256);
  dim3 gbig(M/256, 8);       // 32 x 8 = 256 blocks, 1/CU
  dim3 gns(M/32);            // small K=128 GEMM
  dim3 grt(M/64);            // red_t
  dim3 grr(M*128/(256*8));   // red_r
  dim3 grf(M*128/(256*4));   // red_f
  dim3 gt(128);

  wtrans_k<<<gt, b, 0, stream>>>(W1, W2, W1T, W2T);
  // layer 1
  sgemm<false><<<gns, b, 0, stream>>>(input, W1T, XWT, 128, M);
  gemm_big<<<gbig, b, 0, stream>>>(winv, XWT, P, M, M);
  red_t  <<<grt, b, 0, stream>>>(P, f1, SPT, M);
  gemm_big<<<gbig, b, 0, stream>>>(wav, SPT, P, M, M);
  red_r  <<<grr, b, 0, stream>>>(P, H1, M);
  // layer 2
  sgemm<true ><<<gns, b, 0, stream>>>(H1, W2T, XWT, 128, M);
  gemm_big<<<gbig, b, 0, stream>>>(winv, XWT, P, M, M);
  red_t  <<<grt, b, 0, stream>>>(P, f2, SPT, M);
  gemm_big<<<gbig, b, 0, stream>>>(wav, SPT, P, M, M);
  red_f  <<<grf, b, 0, stream>>>(P, (float*)d_out, M);
}

// Round 21
// 290.945 us; speedup vs baseline: 1.1669x; 1.1194x over previous
//
#include <hip/hip_runtime.h>
#include <hip/hip_bf16.h>
#include <stdint.h>

// GWNN: out = L2(relu(L1(x))),  L(x) = W_wav · diag(f) · W_inv · (x·W)
// R21 = R14 (session best, 290us) + RACE FIX: second s_barrier after COMPUTE
// seals "all waves' LDS reads of buf(t) complete" BEFORE any wave restages
// that buffer at iter t+1. (R20's replay-divergence exposed the latent
// single-barrier restage hazard.) NBUF=3 keeps staging depth unaffected by
// the extra barrier (STAGE precedes COMPUTE). All else identical to R14:
// BM=128, BK=64, split-K x4, T1 XCD swizzle, counted vmcnt(12)/step,
// f32 partials + fused reduce kernels.

typedef __attribute__((ext_vector_type(4))) float f32x4;
typedef __attribute__((ext_vector_type(8))) short s16x8;
typedef __attribute__((ext_vector_type(4))) short s16x4;

#define DEVI static __device__ __forceinline__

DEVI short bf1(float x){ __bf16 h = (__bf16)x; return __builtin_bit_cast(short, h); }

DEVI s16x8 cvt8(f32x4 lo, f32x4 hi){
  s16x8 r;
#pragma unroll
  for (int i = 0; i < 4; ++i){ r[i] = bf1(lo[i]); r[4+i] = bf1(hi[i]); }
  return r;
}

DEVI void glds16(const void* g, void* l){
  __builtin_amdgcn_global_load_lds((const __attribute__((address_space(1))) void*)g,
                                   (__attribute__((address_space(3))) void*)l, 16, 0, 0);
}

template<int N> DEVI void waitvm(){
  if constexpr (N == 0)       asm volatile("s_waitcnt vmcnt(0)"  ::: "memory");
  else if constexpr (N == 5)  asm volatile("s_waitcnt vmcnt(5)"  ::: "memory");
  else if constexpr (N == 6)  asm volatile("s_waitcnt vmcnt(6)"  ::: "memory");
  else if constexpr (N == 12) asm volatile("s_waitcnt vmcnt(12)" ::: "memory");
}

// ============================================================================
// Big GEMM, BM=128, split-K x4: P[kq][M][128] = A[M, kq-quarter](f32) @ Bt^T
// Bt bf16 row-major [128][K]. Wave w owns rows 32w..32w+31: acc[2][8],
// 32 MFMA/wave/step. 12 gload_lds/wave/stage; NBUF=3 ring, PRE=2.
// Per step: waitvm(12); barrier; STAGE(t+2); COMPUTE(t); lgkmcnt(0); barrier.
// The trailing barrier guarantees every wave's reads of buf(t) are complete
// before buf(t) is restaged at iter t+1 (explicit, not scheduling-dependent).
// XCD swizzle: logical m-tile bxl = (bx%8)*8 + bx/8  (bijective, 64 tiles).
// ============================================================================
__global__ __launch_bounds__(256, 1) void gemm_big(
    const float* __restrict__ Ap, const short* __restrict__ Btp,
    float* __restrict__ Pp, int K, int M)
{
  constexpr int BM = 128, BK = 64;
  constexpr int ASZ = BM*BK*4;     // 32 KB fp32 A tile
  constexpr int BSZ = 128*BK*2;    // 16 KB B tile
  constexpr int TSZ = ASZ + BSZ;   // 48 KB
  constexpr int NBUF = 3, PRE = 2; // 144 KB LDS
  __shared__ uint8_t lds[NBUF*TSZ];

  const int tid  = threadIdx.x;
  const int lane = tid & 63;
  const int wv   = tid >> 6;
  const int la   = lane & 15;
  const int g4   = lane >> 4;
  const int bxl  = ((blockIdx.x & 7) << 3) + (blockIdx.x >> 3);  // T1 swizzle
  const int m0   = bxl * BM;
  const int kq   = blockIdx.y;
  const int K4   = K >> 2;
  const int kb   = kq * K4;

  // ---- A staging: wave w, instr j (0..7) stages local rows 32w+4j..+3.
  const float* gAbase = Ap + (size_t)m0*K + kb;
  int aoffg[8];
#pragma unroll
  for (int j = 0; j < 8; ++j){
    const int rl = (wv<<5) + (j<<2) + (lane>>4);        // local row 0..127
    aoffg[j] = rl*K + (((lane&15) ^ (rl&15))<<2);       // float offset
  }

  // ---- B staging (proven): wave w stages rows 32w..32w+31, pre-swizzled
  const int nb0 = (wv<<5) + (lane>>3);
  const short* gB0 = Btp + (size_t)(nb0    )*K + kb + (((lane&7)^(nb0&7))<<3);
  const short* gB1 = Btp + (size_t)(nb0+ 8 )*K + kb + (((lane&7)^(nb0&7))<<3);
  const short* gB2 = Btp + (size_t)(nb0+16 )*K + kb + (((lane&7)^(nb0&7))<<3);
  const short* gB3 = Btp + (size_t)(nb0+24 )*K + kb + (((lane&7)^(nb0&7))<<3);

  // ---- fragment LDS byte offsets (XOR-swizzled reads)
  int aoff[2][2][2];   // [mi][kf][part]; fp32 row = 16 x 16B units
#pragma unroll
  for (int mi = 0; mi < 2; ++mi){
    const int r = (wv<<5) + mi*16 + la;                 // wave-private rows
#pragma unroll
    for (int kf = 0; kf < 2; ++kf){
      const int v0 = kf*8 + (g4<<1);
      aoff[mi][kf][0] = r*256 + (((v0  )^(r&15))<<4);
      aoff[mi][kf][1] = r*256 + (((v0+1)^(r&15))<<4);
    }
  }
  int boff[8][2];      // [ni][kf]; all 128 cols per wave
#pragma unroll
  for (int ni = 0; ni < 8; ++ni){
    const int n = ni*16 + la;
#pragma unroll
    for (int kf = 0; kf < 2; ++kf){
      const int u = kf*4 + g4;
      boff[ni][kf] = n*128 + ((u^(n&7))<<4);
    }
  }

  f32x4 acc[2][8] = {};

  int kk = 0;                                // A k-advance (floats)
  uint8_t* const lend = lds + NBUF*TSZ;
  uint8_t* bs = lds;
  uint8_t* bc = lds;

  auto STAGE = [&](){
    uint8_t* Ab = bs;
    uint8_t* Bb = bs + ASZ;
#pragma unroll
    for (int j = 0; j < 8; ++j)
      glds16(gAbase + aoffg[j] + kk, Ab + (wv<<13) + (j<<10));
    kk += BK;
    glds16(gB0, Bb + (wv<<12));
    glds16(gB1, Bb + (wv<<12) + 1024);
    glds16(gB2, Bb + (wv<<12) + 2048);
    glds16(gB3, Bb + (wv<<12) + 3072);
    gB0 += BK; gB1 += BK; gB2 += BK; gB3 += BK;
    bs += TSZ; if (bs == lend) bs = lds;
  };

  auto COMPUTE = [&](){
    const uint8_t* Ab = bc;
    const uint8_t* Bb = bc + ASZ;
#pragma unroll
    for (int kf = 0; kf < 2; ++kf){
      s16x8 a0 = cvt8(*(const f32x4*)(Ab + aoff[0][kf][0]),
                      *(const f32x4*)(Ab + aoff[0][kf][1]));
      s16x8 a1 = cvt8(*(const f32x4*)(Ab + aoff[1][kf][0]),
                      *(const f32x4*)(Ab + aoff[1][kf][1]));
#pragma unroll
      for (int ni = 0; ni < 8; ++ni){
        s16x8 b = *(const s16x8*)(Bb + boff[ni][kf]);
        acc[0][ni] = __builtin_amdgcn_mfma_f32_16x16x32_bf16(a0, b, acc[0][ni], 0, 0, 0);
        acc[1][ni] = __builtin_amdgcn_mfma_f32_16x16x32_bf16(a1, b, acc[1][ni], 0, 0, 0);
      }
    }
    bc += TSZ; if (bc == lend) bc = lds;
  };

  const int ns = K4 >> 6;                    // 32 steps
  for (int s = 0; s < PRE && s < ns; ++s) STAGE();

  for (int t = 0; t < ns; ++t){
    if (t < ns - 1) waitvm<12>();            // stage t landed; t+1 in flight
    else            waitvm<0>();
    __builtin_amdgcn_s_barrier();            // buf(t) published to all waves
    asm volatile("" ::: "memory");
    if (t + PRE < ns) STAGE();               // restage buf(t-1) (sealed below)
    COMPUTE();
    asm volatile("s_waitcnt lgkmcnt(0)" ::: "memory");  // my reads of buf(t) done
    __builtin_amdgcn_s_barrier();            // ALL waves' reads of buf(t) done
  }

  // ---- partial epilogue: f32 P[kq][M][128]
  float* P = Pp + (size_t)kq * M * 128;
  const int rbase = m0 + (wv<<5) + (g4<<2);
#pragma unroll
  for (int mi = 0; mi < 2; ++mi)
#pragma unroll
    for (int ni = 0; ni < 8; ++ni)
#pragma unroll
      for (int r = 0; r < 4; ++r)
        P[(size_t)(rbase + mi*16 + r)*128 + ni*16 + la] = acc[mi][ni][r];
}

// ============================================================================
// Small K=128 GEMM: out = bf16 transposed [128][M]. Same 2-barrier seal.
// ============================================================================
template<bool ABF>
__global__ __launch_bounds__(256, 1) void sgemm(
    const void* __restrict__ Ap, const short* __restrict__ Btp,
    void* __restrict__ Outp, int K, int M)
{
  constexpr int BM = 32, BN = 128, BK = 64;
  constexpr int ASZ = ABF ? BM*BK*2 : BM*BK*4;
  constexpr int BSZ = BN*BK*2;
  constexpr int TSZ = ASZ + BSZ;
  constexpr int NL  = ABF ? 5 : 6;
  constexpr int NBUF = 3, PRE = 2;
  __shared__ uint8_t lds[NBUF*TSZ];

  const int tid  = threadIdx.x;
  const int lane = tid & 63;
  const int wv   = tid >> 6;
  const int la   = lane & 15;
  const int g4   = lane >> 4;
  const int m0   = blockIdx.x * BM;

  const float* gA0 = nullptr; const float* gA1 = nullptr; const short* gAh = nullptr;
  if constexpr (!ABF){
    const float* Af = (const float*)Ap;
    int r0 = (wv<<3) + (lane>>4);
    int r1 = r0 + 4;
    gA0 = Af + (size_t)(m0+r0)*K + (((lane&15)^(r0&15))<<2);
    gA1 = Af + (size_t)(m0+r1)*K + (((lane&15)^(r1&15))<<2);
  } else {
    const short* Ah = (const short*)Ap;
    int r = (wv<<3) + (lane>>3);
    gAh = Ah + (size_t)(m0+r)*K + (((lane&7)^(r&7))<<3);
  }
  const int nb0 = (wv<<5) + (lane>>3);
  const short* gB0 = Btp + (size_t)(nb0    )*K + (((lane&7)^(nb0&7))<<3);
  const short* gB1 = Btp + (size_t)(nb0+ 8 )*K + (((lane&7)^(nb0&7))<<3);
  const short* gB2 = Btp + (size_t)(nb0+16 )*K + (((lane&7)^(nb0&7))<<3);
  const short* gB3 = Btp + (size_t)(nb0+24 )*K + (((lane&7)^(nb0&7))<<3);

  int aoff[2][2][2];
  int boff[2][2];
#pragma unroll
  for (int mi = 0; mi < 2; ++mi){
    const int r = mi*16 + la;
#pragma unroll
    for (int kf = 0; kf < 2; ++kf){
      if constexpr (!ABF){
        const int v0 = kf*8 + (g4<<1);
        aoff[mi][kf][0] = r*256 + (((v0  )^(r&15))<<4);
        aoff[mi][kf][1] = r*256 + (((v0+1)^(r&15))<<4);
      } else {
        const int u = kf*4 + g4;
        aoff[mi][kf][0] = r*128 + ((u^(r&7))<<4);
        aoff[mi][kf][1] = 0;
      }
    }
  }
#pragma unroll
  for (int ni = 0; ni < 2; ++ni){
    const int n = (wv<<5) + ni*16 + la;
#pragma unroll
    for (int kf = 0; kf < 2; ++kf){
      const int u = kf*4 + g4;
      boff[ni][kf] = n*128 + ((u^(n&7))<<4);
    }
  }

  f32x4 acc[2][2] = {};

  auto STAGE = [&](uint8_t* buf){
    uint8_t* Ab = buf;
    uint8_t* Bb = buf + ASZ;
    if constexpr (!ABF){
      glds16(gA0, Ab + (wv<<11));
      glds16(gA1, Ab + (wv<<11) + 1024);
      gA0 += BK; gA1 += BK;
    } else {
      glds16(gAh, Ab + (wv<<10));
      gAh += BK;
    }
    glds16(gB0, Bb + (wv<<12));
    glds16(gB1, Bb + (wv<<12) + 1024);
    glds16(gB2, Bb + (wv<<12) + 2048);
    glds16(gB3, Bb + (wv<<12) + 3072);
    gB0 += BK; gB1 += BK; gB2 += BK; gB3 += BK;
  };

  auto COMPUTE = [&](const uint8_t* buf){
    const uint8_t* Ab = buf;
    const uint8_t* Bb = buf + ASZ;
#pragma unroll
    for (int kf = 0; kf < 2; ++kf){
      s16x8 a0, a1, b0, b1;
      if constexpr (!ABF){
        a0 = cvt8(*(const f32x4*)(Ab + aoff[0][kf][0]), *(const f32x4*)(Ab + aoff[0][kf][1]));
        a1 = cvt8(*(const f32x4*)(Ab + aoff[1][kf][0]), *(const f32x4*)(Ab + aoff[1][kf][1]));
      } else {
        a0 = *(const s16x8*)(Ab + aoff[0][kf][0]);
        a1 = *(const s16x8*)(Ab + aoff[1][kf][0]);
      }
      b0 = *(const s16x8*)(Bb + boff[0][kf]);
      b1 = *(const s16x8*)(Bb + boff[1][kf]);
      acc[0][0] = __builtin_amdgcn_mfma_f32_16x16x32_bf16(a0, b0, acc[0][0], 0, 0, 0);
      acc[0][1] = __builtin_amdgcn_mfma_f32_16x16x32_bf16(a0, b1, acc[0][1], 0, 0, 0);
      acc[1][0] = __builtin_amdgcn_mfma_f32_16x16x32_bf16(a1, b0, acc[1][0], 0, 0, 0);
      acc[1][1] = __builtin_amdgcn_mfma_f32_16x16x32_bf16(a1, b1, acc[1][1], 0, 0, 0);
    }
  };

  const int ns = K >> 6;
  uint8_t* const lend = lds + NBUF*TSZ;
  uint8_t* bs = lds;
  uint8_t* bc = lds;
  for (int s = 0; s < PRE && s < ns; ++s){
    STAGE(bs);
    bs += TSZ; if (bs == lend) bs = lds;
  }
  for (int t = 0; t < ns; ++t){
    if (t < ns - 1) waitvm<NL>(); else waitvm<0>();
    __builtin_amdgcn_s_barrier();
    asm volatile("" ::: "memory");
    if (t + PRE < ns){
      STAGE(bs);
      bs += TSZ; if (bs == lend) bs = lds;
    }
    COMPUTE(bc);
    bc += TSZ; if (bc == lend) bc = lds;
    asm volatile("s_waitcnt lgkmcnt(0)" ::: "memory");
    __builtin_amdgcn_s_barrier();            // seal reads before restage
  }

  const int mbase = m0 + (g4<<2);
  const int nc0   = (wv<<5) + la;
#pragma unroll
  for (int mi = 0; mi < 2; ++mi){
#pragma unroll
    for (int ni = 0; ni < 2; ++ni){
      s16x4 pk;
#pragma unroll
      for (int r = 0; r < 4; ++r) pk[r] = bf1(acc[mi][ni][r]);
      *(s16x4*)((short*)Outp + (size_t)(nc0 + (ni<<4))*M + (mbase + (mi<<4))) = pk;
    }
  }
}

// ============================================================================
// Reduce kernels: combine 4 K-quarter partials P[4][M][128] (f32).
// ============================================================================

__global__ __launch_bounds__(256) void red_t(
    const float* __restrict__ Pp, const float* __restrict__ fp,
    short* __restrict__ out, int M)
{
  __shared__ short t[128*65];
  const size_t S = (size_t)M*128;
  const int m0 = blockIdx.x * 64;
  const int tid = threadIdx.x;
#pragma unroll
  for (int it = 0; it < 8; ++it){
    const int idx = it*256 + tid;
    const int m = idx >> 5, nq = idx & 31;
    const float* base = Pp + (size_t)(m0+m)*128;
    f32x4 a = ((const f32x4*)(base      ))[nq];
    f32x4 b = ((const f32x4*)(base +   S))[nq];
    f32x4 c = ((const f32x4*)(base + 2*S))[nq];
    f32x4 d = ((const f32x4*)(base + 3*S))[nq];
    const float fv = fp[m0+m];
#pragma unroll
    for (int j = 0; j < 4; ++j)
      t[(nq*4+j)*65 + m] = bf1(fv * ((a[j] + b[j]) + (c[j] + d[j])));
  }
  __syncthreads();
#pragma unroll
  for (int it = 0; it < 8; ++it){
    const int idx = it*256 + tid;
    const int n = idx >> 4, mc = idx & 15;
    s16x4 v;
#pragma unroll
    for (int j = 0; j < 4; ++j) v[j] = t[n*65 + mc*4 + j];
    *(s16x4*)(out + (size_t)n*M + m0 + mc*4) = v;
  }
}

__global__ __launch_bounds__(256) void red_r(
    const float* __restrict__ Pp, short* __restrict__ out, int M)
{
  const size_t S = (size_t)M*128;
  const size_t i0 = (size_t)(blockIdx.x*256 + threadIdx.x) * 8;
  s16x8 v;
#pragma unroll
  for (int h = 0; h < 2; ++h){
    f32x4 a = *(const f32x4*)(Pp + i0 + 4*h);
    f32x4 b = *(const f32x4*)(Pp + i0 + 4*h + S);
    f32x4 c = *(const f32x4*)(Pp + i0 + 4*h + 2*S);
    f32x4 d = *(const f32x4*)(Pp + i0 + 4*h + 3*S);
#pragma unroll
    for (int j = 0; j < 4; ++j)
      v[4*h+j] = bf1(fmaxf((a[j] + b[j]) + (c[j] + d[j]), 0.0f));
  }
  *(s16x8*)(out + i0) = v;
}

__global__ __launch_bounds__(256) void red_f(
    const float* __restrict__ Pp, float* __restrict__ out, int M)
{
  const size_t S = (size_t)M*128;
  const size_t i0 = (size_t)(blockIdx.x*256 + threadIdx.x) * 4;
  f32x4 a = *(const f32x4*)(Pp + i0);
  f32x4 b = *(const f32x4*)(Pp + i0 + S);
  f32x4 c = *(const f32x4*)(Pp + i0 + 2*S);
  f32x4 d = *(const f32x4*)(Pp + i0 + 3*S);
  *(f32x4*)(out + i0) = (a + b) + (c + d);
}

// W1T[n][k] = bf16(W1[k][n]), same for W2 — tiny one-shot transpose.
__global__ void wtrans_k(const float* __restrict__ W1, const float* __restrict__ W2,
                         short* __restrict__ T1, short* __restrict__ T2){
  const int idx = blockIdx.x*256 + threadIdx.x;
  const int m = idx >> 14, rem = idx & 16383;
  const int n = rem >> 7, k = rem & 127;
  const float* W = m ? W2 : W1;
  short* T = m ? T2 : T1;
  T[n*128 + k] = bf1(W[k*128 + n]);
}

extern "C" void kernel_launch(void* const* d_in, const int* in_sizes, int n_in,
                              void* d_out, int out_size, void* d_ws, size_t ws_size,
                              hipStream_t stream){
  const float* input = (const float*)d_in[0];
  const float* wav   = (const float*)d_in[1];
  const float* winv  = (const float*)d_in[2];
  const float* W1    = (const float*)d_in[3];
  const float* f1    = (const float*)d_in[4];
  const float* W2    = (const float*)d_in[5];
  const float* f2    = (const float*)d_in[6];

  constexpr int M = 8192;
  uint8_t* ws = (uint8_t*)d_ws;
  short* W1T = (short*)(ws);                        // 32 KB  [n][k]
  short* W2T = (short*)(ws + (32<<10));             // 32 KB  [n][k]
  short* XWT = (short*)(ws + (64<<10));             // 2 MB   [128][M] bf16
  short* SPT = (short*)(ws + (64<<10) + (2<<20));   // 2 MB   [128][M] bf16
  short* H1  = (short*)(ws + (64<<10) + (4<<20));   // 2 MB   [M][128] bf16
  float* P   = (float*)(ws + (64<<10) + (6<<20));   // 16 MB  f32 [4][M][128]

  dim3 b(256);
  dim3 gbig(M/128, 4);       // 64 x 4 = 256 blocks, 1/CU
  dim3 gns(M/32);            // small K=128 GEMM
  dim3 grt(M/64);            // red_t
  dim3 grr(M*128/(256*8));   // red_r
  dim3 grf(M*128/(256*4));   // red_f
  dim3 gt(128);

  wtrans_k<<<gt, b, 0, stream>>>(W1, W2, W1T, W2T);
  // layer 1
  sgemm<false><<<gns, b, 0, stream>>>(input, W1T, XWT, 128, M);
  gemm_big<<<gbig, b, 0, stream>>>(winv, XWT, P, M, M);
  red_t  <<<grt, b, 0, stream>>>(P, f1, SPT, M);
  gemm_big<<<gbig, b, 0, stream>>>(wav, SPT, P, M, M);
  red_r  <<<grr, b, 0, stream>>>(P, H1, M);
  // layer 2
  sgemm<true ><<<gns, b, 0, stream>>>(H1, W2T, XWT, 128, M);
  gemm_big<<<gbig, b, 0, stream>>>(winv, XWT, P, M, M);
  red_t  <<<grt, b, 0, stream>>>(P, f2, SPT, M);
  gemm_big<<<gbig, b, 0, stream>>>(wav, SPT, P, M, M);
  red_f  <<<grf, b, 0, stream>>>(P, (float*)d_out, M);
}